// Round 11
// baseline (3539.786 us; speedup 1.0000x reference)
//
#include <hip/hip_runtime.h>
#include <hip/hip_bf16.h>

// LSTM B=32,T=512,D=512,H=1024, persistent kernel.
// R14 = R11 + x-projection as fused producers with a RING buffer sized to
// the actual workspace (R13's 256MB flat xproj never fit; its XP=0
// fallback ran = exact R11. R13's producer tile math was also wrong --
// rebuilt here as a literal clone of R11's proven x-part addressing).
//  - xproj ring: W timesteps (power of 2, adaptive from ws_size; min 16,
//    cap 512), 512KB/step. Blocks 64..255 grid-stride items (t, nc) in
//    t-ascending order; per item: compute 8x(16-col, full-K=512) tiles
//    (one per wave, b=lcol/lcol+16 A-fragments exactly as R11 x-part),
//    THROTTLE (all 64 consumer flags >= t-W+1 -> slot's previous reader
//    done), store f32 agent-atomics -> vmcnt(0) -> syncthreads -> tid0
//    fetch_add(counters[t]). Consumer gates step t on counters[t]==32,
//    reads xp from slot t&(W-1); gate+xp latency hides under the h poll.
//  - Deadlock-free: items globally t-ascending per producer; any item at
//    time <= consumer's t has throttle satisfied, so counters[t] fills.
//  - Consumer loop: h-only MFMAs (64/wave/step, was 96), wreg[16].
//  - XP=0 fallback (ws < ~55MB): EXACT R11 (3275us).
//  - h protocol EXACTLY R11: subset poll, wave0 4x512B 8B-atomic store
//    bursts, own-vmcnt drain, flag; syncA + syncC.

#define B_   32
#define T_   512
#define D_   512
#define H_   1024
#define KTOT 1536
#define N4H  4096
#define NBLK 64
#define NPROD 192
#define NITEM (T_ * 32)   // (t, nc) items; nc = 128-col chunk

typedef __bf16 bf16_t;
typedef __bf16 bf16x8 __attribute__((ext_vector_type(8)));
typedef float f32x4 __attribute__((ext_vector_type(4)));

#define MFMA16(a, b, c) __builtin_amdgcn_mfma_f32_16x16x32_bf16(a, b, c, 0, 0, 0)

// ---------------------------------------------------------------------------
__global__ void wconv_kernel(const float* __restrict__ Wx,
                             const float* __restrict__ Wh,
                             bf16_t* __restrict__ Wt) {
    __shared__ float tile[32][33];
    int k0 = blockIdx.x * 32;
    int n0 = blockIdx.y * 32;
    int tx = threadIdx.x;
    int ty = threadIdx.y;
    for (int i = ty; i < 32; i += 8) {
        int k = k0 + i;
        float v = (k < H_) ? Wh[(size_t)k * N4H + n0 + tx]
                           : Wx[(size_t)(k - H_) * N4H + n0 + tx];
        tile[i][tx] = v;
    }
    __syncthreads();
    for (int i = ty; i < 32; i += 8)
        Wt[(size_t)(n0 + i) * KTOT + k0 + tx] = (bf16_t)tile[tx][i];
}

// ---------------------------------------------------------------------------
// X -> packed uint32 per element: low16 = bf16(hi), high16 = bf16(residual).
__global__ void xconv_kernel(const float4* __restrict__ X,
                             uint4* __restrict__ Xpk) {
    int i = blockIdx.x * blockDim.x + threadIdx.x;
    float4 v = X[i];
    float arr[4] = {v.x, v.y, v.z, v.w};
    unsigned pk[4];
#pragma unroll
    for (int j = 0; j < 4; ++j) {
        bf16_t h = (bf16_t)arr[j];
        bf16_t l = (bf16_t)(arr[j] - (float)h);
        pk[j] = (unsigned)__builtin_bit_cast(unsigned short, h) |
                ((unsigned)__builtin_bit_cast(unsigned short, l) << 16);
    }
    Xpk[i] = make_uint4(pk[0], pk[1], pk[2], pk[3]);
}

// ---------------------------------------------------------------------------
__device__ __forceinline__ void unpack16(const unsigned short* s,
                                         bf16x8* hi, bf16x8* lo) {
#pragma unroll
    for (int j = 0; j < 8; ++j) {
        (*hi)[j] = __builtin_bit_cast(bf16_t, s[2 * j]);
        (*lo)[j] = __builtin_bit_cast(bf16_t, s[2 * j + 1]);
    }
}

// ---------------------------------------------------------------------------
template <int XP>
__global__ __launch_bounds__(512, 1) void lstm_kernel(
    const bf16_t* __restrict__ Wt,
    const unsigned* __restrict__ Xpk,
    float* __restrict__ xproj,
    unsigned* __restrict__ hpk,
    const float* __restrict__ bias,
    const int* __restrict__ seqlen,
    float* __restrict__ out,
    unsigned* __restrict__ flags,
    unsigned* __restrict__ counters,
    int Wm1) {
    __shared__ float zpart[8][4][32][16];  // 64 KB partial sums
    __shared__ unsigned stage[512];        // 2 KB h-store stage

    const int tid  = threadIdx.x;
    const int w    = tid >> 6;
    const int lane = tid & 63;
    const int quad = lane >> 4;
    const int lcol = lane & 15;

    // ---------------- producer role (XP=1, blocks 64..255) ----------------
    if (XP && (int)blockIdx.x >= NBLK) {
#pragma unroll 1
        for (int item = (int)blockIdx.x - NBLK; item < NITEM; item += NPROD) {
            const int t  = item >> 5;
            const int nc = item & 31;
            const int n0 = nc * 128 + w * 16;      // 16 output cols per wave
            bf16x8 wr[16];
#pragma unroll
            for (int kk = 0; kk < 16; ++kk)
                wr[kk] = *(const bf16x8*)(Wt + (size_t)(n0 + lcol) * KTOT +
                                          1024 + kk * 32 + quad * 8);
            f32x4 acc0 = {0.f, 0.f, 0.f, 0.f};    // batches 0..15
            f32x4 acc1 = {0.f, 0.f, 0.f, 0.f};    // batches 16..31
#pragma unroll 4
            for (int kk = 0; kk < 16; ++kk) {
                union { uint4 q[2]; unsigned short s[16]; } u0, u1;
                const unsigned* p0 =
                    Xpk + ((size_t)lcol * T_ + t) * D_ + kk * 32 + quad * 8;
                const unsigned* p1 =
                    Xpk + ((size_t)(lcol + 16) * T_ + t) * D_ + kk * 32 + quad * 8;
                u0.q[0] = *(const uint4*)p0;
                u0.q[1] = *(const uint4*)(p0 + 4);
                u1.q[0] = *(const uint4*)p1;
                u1.q[1] = *(const uint4*)(p1 + 4);
                bf16x8 a0h, a0l, a1h, a1l;
                unpack16(u0.s, &a0h, &a0l);
                unpack16(u1.s, &a1h, &a1l);
                acc0 = MFMA16(a0h, wr[kk], acc0);
                acc0 = MFMA16(a0l, wr[kk], acc0);
                acc1 = MFMA16(a1h, wr[kk], acc1);
                acc1 = MFMA16(a1l, wr[kk], acc1);
            }
            // Throttle AFTER compute, before store: slot's previous reader
            // (consumer step t-W) must be done -> all flags >= t-W+1.
            const int thr = t - (Wm1 + 1) + 1;
            if (thr > 0) {
                const unsigned* fp = flags + (lane >> 3) * 16 + (lane & 7);
                for (;;) {
                    unsigned v = __hip_atomic_load(fp, __ATOMIC_RELAXED,
                                                   __HIP_MEMORY_SCOPE_AGENT);
                    if (__all((int)v >= thr)) break;
                    __builtin_amdgcn_s_sleep(2);
                }
                asm volatile("" ::: "memory");
            }
            const int slot = t & Wm1;
            float* xb = xproj + (size_t)slot * B_ * N4H + n0 + lcol;
#pragma unroll
            for (int r = 0; r < 4; ++r) {
                __hip_atomic_store(xb + (size_t)(quad * 4 + r) * N4H, acc0[r],
                                   __ATOMIC_RELAXED, __HIP_MEMORY_SCOPE_AGENT);
                __hip_atomic_store(xb + (size_t)(16 + quad * 4 + r) * N4H,
                                   acc1[r], __ATOMIC_RELAXED,
                                   __HIP_MEMORY_SCOPE_AGENT);
            }
            asm volatile("s_waitcnt vmcnt(0)" ::: "memory");
            __syncthreads();   // all 8 waves' stores drained
            if (tid == 0)
                __hip_atomic_fetch_add(counters + t, 1u, __ATOMIC_RELAXED,
                                       __HIP_MEMORY_SCOPE_AGENT);
        }
        return;
    }

    // ---------------- consumer / recurrent loop (blocks 0..63) -------------
    const int hc0 = blockIdx.x * 16;
    const int HW_ = 32768;                 // uints per h buffer (B_*H_)

    bf16x8 wreg[XP ? 16 : 24];
    if (XP) {
#pragma unroll
        for (int g = 0; g < 4; ++g)
#pragma unroll
            for (int it = 0; it < 4; ++it)
                wreg[g * 4 + it] = *(const bf16x8*)(
                    Wt + (size_t)(g * H_ + hc0 + lcol) * KTOT + w * 128 +
                    it * 32 + quad * 8);
    } else {
#pragma unroll
        for (int g = 0; g < 4; ++g)
#pragma unroll
            for (int it = 0; it < 6; ++it) {
                int k = (it < 4) ? (w * 128 + it * 32)
                                 : (1024 + w * 64 + (it - 4) * 32);
                wreg[g * 6 + it] = *(const bf16x8*)(
                    Wt + (size_t)(g * H_ + hc0 + lcol) * KTOT + k + quad * 8);
            }
    }

    const int eb = tid >> 4, ec = tid & 15;
    const int col = hc0 + ec;
    float creg = 0.f;
    const float b0 = bias[col];
    const float b1 = bias[H_ + col];
    const float b2 = bias[2 * H_ + col];
    const float b3 = bias[3 * H_ + col];
    const int slm1 = seqlen[eb] - 1;
    const int stageIdx = (eb >> 4) * 256 + ((ec >> 3) * 16 + (eb & 15)) * 8 +
                         (ec & 7);
    const int kbB  = (hc0 >> 5) * 1024;
    const int qlo  = (hc0 >> 4) & 1;
    const int QU   = (kbB >> 1) + qlo * 128;
    const int myflag = ((blockIdx.x >> 3) << 4) | (blockIdx.x & 7);
    const unsigned* pollp = flags + w * 16 + (lane & 7);

#pragma unroll 1
    for (int t = 0; t < T_; ++t) {
        const unsigned* hr = hpk + (size_t)(t & 1) * HW_;
        unsigned*       hw = hpk + (size_t)((t + 1) & 1) * HW_;

        f32x4 acc[8];
#pragma unroll
        for (int i = 0; i < 8; ++i) acc[i] = (f32x4){0.f, 0.f, 0.f, 0.f};

        float xp0, xp1, xp2, xp3;
        if (XP) {
            // Gate on producers of step t, then fetch xp from ring slot.
            {
                const unsigned* cp = counters + t;
                while (__hip_atomic_load(cp, __ATOMIC_RELAXED,
                                         __HIP_MEMORY_SCOPE_AGENT) < 32u)
                    __builtin_amdgcn_s_sleep(1);
                asm volatile("" ::: "memory");
            }
            const float* xpt =
                xproj + (size_t)((t & Wm1) * B_ + eb) * N4H + col;
            xp0 = __hip_atomic_load(xpt, __ATOMIC_RELAXED,
                                    __HIP_MEMORY_SCOPE_AGENT);
            xp1 = __hip_atomic_load(xpt + H_, __ATOMIC_RELAXED,
                                    __HIP_MEMORY_SCOPE_AGENT);
            xp2 = __hip_atomic_load(xpt + 2 * H_, __ATOMIC_RELAXED,
                                    __HIP_MEMORY_SCOPE_AGENT);
            xp3 = __hip_atomic_load(xpt + 3 * H_, __ATOMIC_RELAXED,
                                    __HIP_MEMORY_SCOPE_AGENT);
        } else {
            xp0 = xp1 = xp2 = xp3 = 0.f;
#pragma unroll
            for (int itx = 0; itx < 2; ++itx) {
                int kx = w * 64 + itx * 32 + quad * 8;
                union { uint4 q[2]; unsigned short s[16]; } u0, u1;
                const unsigned* p0 = Xpk + ((size_t)lcol * T_ + t) * D_ + kx;
                const unsigned* p1 =
                    Xpk + ((size_t)(lcol + 16) * T_ + t) * D_ + kx;
                u0.q[0] = *(const uint4*)p0;
                u0.q[1] = *(const uint4*)(p0 + 4);
                u1.q[0] = *(const uint4*)p1;
                u1.q[1] = *(const uint4*)(p1 + 4);
                bf16x8 a0h, a0l, a1h, a1l;
                unpack16(u0.s, &a0h, &a0l);
                unpack16(u1.s, &a1h, &a1l);
#pragma unroll
                for (int g = 0; g < 4; ++g) {
                    bf16x8 wv = wreg[g * 6 + 4 + itx];
                    acc[g * 2]     = MFMA16(a0h, wv, acc[g * 2]);
                    acc[g * 2]     = MFMA16(a0l, wv, acc[g * 2]);
                    acc[g * 2 + 1] = MFMA16(a1h, wv, acc[g * 2 + 1]);
                    acc[g * 2 + 1] = MFMA16(a1l, wv, acc[g * 2 + 1]);
                }
            }
        }

        // ---- wait for THIS wave's 8 h-producers only (tight spin) ----
        {
            const unsigned tgt = (unsigned)t;
            for (;;) {
                unsigned v = __hip_atomic_load(pollp, __ATOMIC_RELAXED,
                                               __HIP_MEMORY_SCOPE_AGENT);
                if (__all((int)(v >= tgt))) break;
            }
            asm volatile("" ::: "memory");
        }

        // ---- h part: issue all 8 fragment loads, then unpack + MFMA ----
        union Raw { unsigned long long u[4]; unsigned short s[16]; };
        Raw r[8];
#pragma unroll
        for (int it = 0; it < 4; ++it) {
            const unsigned long long* q = (const unsigned long long*)(
                hr + (w * 4 + it) * 1024 + lane * 8);
#pragma unroll
            for (int j = 0; j < 4; ++j)
                r[it * 2].u[j] = __hip_atomic_load(
                    q + j, __ATOMIC_RELAXED, __HIP_MEMORY_SCOPE_AGENT);
#pragma unroll
            for (int j = 0; j < 4; ++j)
                r[it * 2 + 1].u[j] = __hip_atomic_load(
                    q + 256 + j, __ATOMIC_RELAXED, __HIP_MEMORY_SCOPE_AGENT);
        }
#pragma unroll
        for (int it = 0; it < 4; ++it) {
            bf16x8 a0h, a0l, a1h, a1l;
            unpack16(r[it * 2].s, &a0h, &a0l);
            unpack16(r[it * 2 + 1].s, &a1h, &a1l);
#pragma unroll
            for (int g = 0; g < 4; ++g) {
                bf16x8 wv = XP ? wreg[g * 4 + it] : wreg[g * 6 + it];
                acc[g * 2]     = MFMA16(a0h, wv, acc[g * 2]);
                acc[g * 2]     = MFMA16(a0l, wv, acc[g * 2]);
                acc[g * 2 + 1] = MFMA16(a1h, wv, acc[g * 2 + 1]);
                acc[g * 2 + 1] = MFMA16(a1l, wv, acc[g * 2 + 1]);
            }
        }

#pragma unroll
        for (int g = 0; g < 4; ++g)
#pragma unroll
            for (int r4 = 0; r4 < 4; ++r4) {
                zpart[w][g][quad * 4 + r4][lcol]      = acc[g * 2][r4];
                zpart[w][g][16 + quad * 4 + r4][lcol] = acc[g * 2 + 1][r4];
            }
        __syncthreads();  // A: zpart complete

        float zi = b0 + xp0, zf = b1 + xp1, zg = b2 + xp2, zo = b3 + xp3;
#pragma unroll
        for (int ss = 0; ss < 8; ++ss) {
            zi += zpart[ss][0][eb][ec];
            zf += zpart[ss][1][eb][ec];
            zg += zpart[ss][2][eb][ec];
            zo += zpart[ss][3][eb][ec];
        }
        float ig = 1.f / (1.f + __expf(-zi));
        float fg = 1.f / (1.f + __expf(-zf));
        float og = 1.f / (1.f + __expf(-zo));
        float gg = 1.f - 2.f / (__expf(2.f * zg) + 1.f);
        creg = fg * creg + ig * gg;
        float hn = og * (1.f - 2.f / (__expf(2.f * creg) + 1.f));
        bf16_t hh = (bf16_t)hn;
        bf16_t hl = (bf16_t)(hn - (float)hh);
        unsigned pk = (unsigned)__builtin_bit_cast(unsigned short, hh) |
                      ((unsigned)__builtin_bit_cast(unsigned short, hl) << 16);
        stage[stageIdx] = pk;
        if (slm1 == t) out[eb * H_ + col] = hn;

        __syncthreads();  // C: stage complete (zpart reads also done)

        if (w == 0) {
            const unsigned long long* sp = (const unsigned long long*)stage;
            unsigned long long* hwu = (unsigned long long*)hw;
#pragma unroll
            for (int j = 0; j < 4; ++j) {
                unsigned long long val = sp[j * 64 + lane];
                __hip_atomic_store(
                    hwu + QU + (j >> 1) * 256 + (j & 1) * 64 + lane, val,
                    __ATOMIC_RELAXED, __HIP_MEMORY_SCOPE_AGENT);
            }
            asm volatile("s_waitcnt vmcnt(0)" ::: "memory");
            if (lane == 0)
                __hip_atomic_store(flags + myflag, (unsigned)(t + 1),
                                   __ATOMIC_RELAXED, __HIP_MEMORY_SCOPE_AGENT);
        }
    }
}

// ---------------------------------------------------------------------------
extern "C" void kernel_launch(void* const* d_in, const int* in_sizes, int n_in,
                              void* d_out, int out_size, void* d_ws, size_t ws_size,
                              hipStream_t stream) {
    const float* inputs = (const float*)d_in[0];
    const int*   seqlen = (const int*)d_in[1];
    const float* Wx     = (const float*)d_in[2];
    const float* Wh     = (const float*)d_in[3];
    const float* bias   = (const float*)d_in[4];
    float* out = (float*)d_out;

    char* ws = (char*)d_ws;
    size_t o = 0;
    bf16_t*   Wt    = (bf16_t*)(ws + o);   o += (size_t)N4H * KTOT * 2;   // 12.6MB
    unsigned* Xpk   = (unsigned*)(ws + o); o += (size_t)B_ * T_ * D_ * 4; // 33.6MB
    unsigned* hpk   = (unsigned*)(ws + o); o += (size_t)2 * B_ * H_ * 4;  // 256KB
    unsigned* flags = (unsigned*)(ws + o); o += 4096;
    unsigned* cnts  = (unsigned*)(ws + o); o += 4096;
    float*    xproj = (float*)(ws + o);

    // Ring W: largest power of 2 slots that fit; min 16, cap 512 (=full T).
    const size_t stepB = (size_t)B_ * N4H * 4;    // 512KB per timestep
    int W = 0;
    if (ws_size > o) {
        size_t avail = (ws_size - o) / stepB;
        for (int cand = 512; cand >= 16; cand >>= 1)
            if ((size_t)cand <= avail) { W = cand; break; }
    }

    wconv_kernel<<<dim3(48, 128), dim3(32, 8), 0, stream>>>(Wx, Wh, Wt);
    xconv_kernel<<<(B_ * T_ * D_ / 4) / 256, 256, 0, stream>>>(
        (const float4*)inputs, (uint4*)Xpk);
    hipMemsetAsync(hpk, 0, (size_t)B_ * H_ * 4, stream);  // ping p=0 zeros
    hipMemsetAsync(flags, 0, 8192, stream);               // flags + counters

    if (W >= 16)
        lstm_kernel<1><<<NBLK + NPROD, 512, 0, stream>>>(
            Wt, Xpk, xproj, hpk, bias, seqlen, out, flags, cnts, W - 1);
    else
        lstm_kernel<0><<<NBLK, 512, 0, stream>>>(
            Wt, Xpk, xproj, hpk, bias, seqlen, out, flags, cnts, 0);
}

// Round 12
// 3448.730 us; speedup vs baseline: 1.0264x; 1.0264x over previous
//
#include <hip/hip_runtime.h>
#include <hip/hip_bf16.h>

// LSTM B=32,T=512,D=512,H=1024, persistent kernel.
// R15 = R11 with the h store-stage apparatus DELETED.
//  Key insight (address audit): thread (eb,ec)'s packed h-word maps to
//  frag-major uint index kbB + (eb>>4)*512 + ((2*qlo+(ec>>3))*16 +
//  (eb&15))*8 + (ec&7); per wave these form TWO contiguous 128B runs ->
//  a direct per-thread 4B agent store is already full-line coalesced.
//  The stage LDS + syncC + wave0's 4 serialized 512B bursts were never
//  needed.
//  - Producer tail per wave: 1x 4B agent store -> own vmcnt(0) (one
//    store; 8 waves drain in PARALLEL) -> lane0 posts flags[bid*8+w].
//  - Consumer wave w polls its 64 producer-wave flags = contiguous
//    flags[64w + lane], one 64-lane load, tight spin.
//  - Safety: union of a block's 8 wave-polls covers all 512 wave-flags
//    before syncA -> ping-pong overwrite invariant identical to R11.
//    Flags order after that wave's h-frag reads (program order), so
//    flag>=t+1 still implies "done reading buf[t&1]".
//  - Barriers: 2/step (syncA after zpart writes; syncB after zpart
//    reads, replacing syncC's LDS-reuse role).
//  - R14's producer/consumer xproj line KILLED: removing 1/3 of consumer
//    MFMAs changed nothing -> period is pinned by this exchange chain.
//  - Everything else EXACTLY R11: x-part before poll, wreg[24], 8B
//    agent-atomic h loads, zpart [32][16].

#define B_   32
#define T_   512
#define D_   512
#define H_   1024
#define KTOT 1536
#define N4H  4096
#define NBLK 64

typedef __bf16 bf16_t;
typedef __bf16 bf16x8 __attribute__((ext_vector_type(8)));
typedef float f32x4 __attribute__((ext_vector_type(4)));

#define MFMA16(a, b, c) __builtin_amdgcn_mfma_f32_16x16x32_bf16(a, b, c, 0, 0, 0)

// ---------------------------------------------------------------------------
__global__ void wconv_kernel(const float* __restrict__ Wx,
                             const float* __restrict__ Wh,
                             bf16_t* __restrict__ Wt) {
    __shared__ float tile[32][33];
    int k0 = blockIdx.x * 32;
    int n0 = blockIdx.y * 32;
    int tx = threadIdx.x;
    int ty = threadIdx.y;
    for (int i = ty; i < 32; i += 8) {
        int k = k0 + i;
        float v = (k < H_) ? Wh[(size_t)k * N4H + n0 + tx]
                           : Wx[(size_t)(k - H_) * N4H + n0 + tx];
        tile[i][tx] = v;
    }
    __syncthreads();
    for (int i = ty; i < 32; i += 8)
        Wt[(size_t)(n0 + i) * KTOT + k0 + tx] = (bf16_t)tile[tx][i];
}

// ---------------------------------------------------------------------------
// X -> packed uint32 per element: low16 = bf16(hi), high16 = bf16(residual).
__global__ void xconv_kernel(const float4* __restrict__ X,
                             uint4* __restrict__ Xpk) {
    int i = blockIdx.x * blockDim.x + threadIdx.x;
    float4 v = X[i];
    float arr[4] = {v.x, v.y, v.z, v.w};
    unsigned pk[4];
#pragma unroll
    for (int j = 0; j < 4; ++j) {
        bf16_t h = (bf16_t)arr[j];
        bf16_t l = (bf16_t)(arr[j] - (float)h);
        pk[j] = (unsigned)__builtin_bit_cast(unsigned short, h) |
                ((unsigned)__builtin_bit_cast(unsigned short, l) << 16);
    }
    Xpk[i] = make_uint4(pk[0], pk[1], pk[2], pk[3]);
}

// ---------------------------------------------------------------------------
__device__ __forceinline__ void unpack16(const unsigned short* s,
                                         bf16x8* hi, bf16x8* lo) {
#pragma unroll
    for (int j = 0; j < 8; ++j) {
        (*hi)[j] = __builtin_bit_cast(bf16_t, s[2 * j]);
        (*lo)[j] = __builtin_bit_cast(bf16_t, s[2 * j + 1]);
    }
}

// ---------------------------------------------------------------------------
// Block b owns h-cols [16b,16b+16). Wave w: h-k in [128w,128w+128) (4 kb,
// producer waves = blocks 8w..8w+7 x 8 waves) + x-k (2 kb). hpk ping-pong,
// frag-major layout, accessed only via agent-scope ops.
__global__ __launch_bounds__(512, 2) void lstm_kernel(
    const bf16_t* __restrict__ Wt,
    const unsigned* __restrict__ Xpk,
    unsigned* __restrict__ hpk,
    const float* __restrict__ bias,
    const int* __restrict__ seqlen,
    float* __restrict__ out,
    unsigned* __restrict__ flags) {
    __shared__ float zpart[8][4][32][16];  // 64 KB partial sums (stride 16:
                                           // epilogue reads exactly 2-way)

    const int tid  = threadIdx.x;
    const int w    = tid >> 6;
    const int lane = tid & 63;
    const int quad = lane >> 4;
    const int lcol = lane & 15;
    const int hc0  = blockIdx.x * 16;
    const int HW_  = 32768;                // uints per h buffer (B_*H_)

    // Weight fragments: 4 gates x 6 k-iters (4 h + 2 x), loaded once.
    bf16x8 wreg[24];
#pragma unroll
    for (int g = 0; g < 4; ++g)
#pragma unroll
        for (int it = 0; it < 6; ++it) {
            int k = (it < 4) ? (w * 128 + it * 32)
                             : (1024 + w * 64 + (it - 4) * 32);
            wreg[g * 6 + it] = *(const bf16x8*)(
                Wt + (size_t)(g * H_ + hc0 + lcol) * KTOT + k + quad * 8);
        }

    // Epilogue mapping: 512 threads = one (batch,col) element each.
    const int eb = tid >> 4, ec = tid & 15;
    const int col = hc0 + ec;
    float creg = 0.f;
    const float b0 = bias[col];
    const float b1 = bias[H_ + col];
    const float b2 = bias[2 * H_ + col];
    const float b3 = bias[3 * H_ + col];
    const int slm1 = seqlen[eb] - 1;
    // Direct frag-major h-store index for this thread (uint units).
    const int kbB  = (hc0 >> 5) * 1024;
    const int qlo  = (hc0 >> 4) & 1;
    const int dstIdx = kbB + (eb >> 4) * 512 +
                       ((2 * qlo + (ec >> 3)) * 16 + (eb & 15)) * 8 + (ec & 7);
    // Per-wave flags: producer wave (b, wv) -> flags[b*8 + wv]. Consumer
    // wave w polls the contiguous 64-entry range flags[64w .. 64w+64).
    const int myflag = blockIdx.x * 8 + w;
    const unsigned* pollp = flags + w * 64 + lane;

#pragma unroll 1
    for (int t = 0; t < T_; ++t) {
        const unsigned* hr = hpk + (size_t)(t & 1) * HW_;
        unsigned*       hw = hpk + (size_t)((t + 1) & 1) * HW_;

        f32x4 acc[8];
#pragma unroll
        for (int i = 0; i < 8; ++i) acc[i] = (f32x4){0.f, 0.f, 0.f, 0.f};

        // ---- x part: independent of h(t-1), fills the wait window ----
#pragma unroll
        for (int itx = 0; itx < 2; ++itx) {
            int kx = w * 64 + itx * 32 + quad * 8;
            union { uint4 q[2]; unsigned short s[16]; } u0, u1;
            const unsigned* p0 = Xpk + ((size_t)lcol * T_ + t) * D_ + kx;
            const unsigned* p1 = Xpk + ((size_t)(lcol + 16) * T_ + t) * D_ + kx;
            u0.q[0] = *(const uint4*)p0;
            u0.q[1] = *(const uint4*)(p0 + 4);
            u1.q[0] = *(const uint4*)p1;
            u1.q[1] = *(const uint4*)(p1 + 4);
            bf16x8 a0h, a0l, a1h, a1l;
            unpack16(u0.s, &a0h, &a0l);
            unpack16(u1.s, &a1h, &a1l);
#pragma unroll
            for (int g = 0; g < 4; ++g) {
                bf16x8 wv = wreg[g * 6 + 4 + itx];
                acc[g * 2]     = MFMA16(a0h, wv, acc[g * 2]);
                acc[g * 2]     = MFMA16(a0l, wv, acc[g * 2]);
                acc[g * 2 + 1] = MFMA16(a1h, wv, acc[g * 2 + 1]);
                acc[g * 2 + 1] = MFMA16(a1l, wv, acc[g * 2 + 1]);
            }
        }

        // ---- wait for THIS wave's 64 producer waves (tight spin) ----
        {
            const unsigned tgt = (unsigned)t;
            for (;;) {
                unsigned v = __hip_atomic_load(pollp, __ATOMIC_RELAXED,
                                               __HIP_MEMORY_SCOPE_AGENT);
                if (__all((int)(v >= tgt))) break;
            }
            asm volatile("" ::: "memory");
        }

        // ---- h part: issue all 8 fragment loads, then unpack + MFMA ----
        union Raw { unsigned long long u[4]; unsigned short s[16]; };
        Raw r[8];
#pragma unroll
        for (int it = 0; it < 4; ++it) {
            const unsigned long long* q = (const unsigned long long*)(
                hr + (w * 4 + it) * 1024 + lane * 8);
#pragma unroll
            for (int j = 0; j < 4; ++j)
                r[it * 2].u[j] = __hip_atomic_load(
                    q + j, __ATOMIC_RELAXED, __HIP_MEMORY_SCOPE_AGENT);
#pragma unroll
            for (int j = 0; j < 4; ++j)
                r[it * 2 + 1].u[j] = __hip_atomic_load(
                    q + 256 + j, __ATOMIC_RELAXED, __HIP_MEMORY_SCOPE_AGENT);
        }
#pragma unroll
        for (int it = 0; it < 4; ++it) {
            bf16x8 a0h, a0l, a1h, a1l;
            unpack16(r[it * 2].s, &a0h, &a0l);
            unpack16(r[it * 2 + 1].s, &a1h, &a1l);
#pragma unroll
            for (int g = 0; g < 4; ++g) {
                bf16x8 wv = wreg[g * 6 + it];
                acc[g * 2]     = MFMA16(a0h, wv, acc[g * 2]);
                acc[g * 2]     = MFMA16(a0l, wv, acc[g * 2]);
                acc[g * 2 + 1] = MFMA16(a1h, wv, acc[g * 2 + 1]);
                acc[g * 2 + 1] = MFMA16(a1l, wv, acc[g * 2 + 1]);
            }
        }

#pragma unroll
        for (int g = 0; g < 4; ++g)
#pragma unroll
            for (int r4 = 0; r4 < 4; ++r4) {
                zpart[w][g][quad * 4 + r4][lcol]      = acc[g * 2][r4];
                zpart[w][g][16 + quad * 4 + r4][lcol] = acc[g * 2 + 1][r4];
            }
        __syncthreads();  // A: zpart complete

        // Epilogue (all 512 threads).
        float zi = b0, zf = b1, zg = b2, zo = b3;
#pragma unroll
        for (int ss = 0; ss < 8; ++ss) {
            zi += zpart[ss][0][eb][ec];
            zf += zpart[ss][1][eb][ec];
            zg += zpart[ss][2][eb][ec];
            zo += zpart[ss][3][eb][ec];
        }
        float ig = 1.f / (1.f + __expf(-zi));
        float fg = 1.f / (1.f + __expf(-zf));
        float og = 1.f / (1.f + __expf(-zo));
        float gg = 1.f - 2.f / (__expf(2.f * zg) + 1.f);
        creg = fg * creg + ig * gg;
        float hn = og * (1.f - 2.f / (__expf(2.f * creg) + 1.f));
        bf16_t hh = (bf16_t)hn;
        bf16_t hl = (bf16_t)(hn - (float)hh);
        unsigned pk = (unsigned)__builtin_bit_cast(unsigned short, hh) |
                      ((unsigned)__builtin_bit_cast(unsigned short, hl) << 16);
        if (slm1 == t) out[eb * H_ + col] = hn;

        // Direct frag-major h store: one 4B agent store per thread; per
        // wave the 64 addresses form two contiguous 128B runs (full-line
        // coalesced). Then each wave drains its OWN single store and
        // posts its OWN flag -- fully wave-parallel tail, no stage.
        __hip_atomic_store(hw + dstIdx, pk, __ATOMIC_RELAXED,
                           __HIP_MEMORY_SCOPE_AGENT);
        asm volatile("s_waitcnt vmcnt(0)" ::: "memory");
        if (lane == 0)
            __hip_atomic_store(flags + myflag, (unsigned)(t + 1),
                               __ATOMIC_RELAXED, __HIP_MEMORY_SCOPE_AGENT);

        __syncthreads();  // B: zpart reads done -> safe to rewrite next step
    }
}

// ---------------------------------------------------------------------------
extern "C" void kernel_launch(void* const* d_in, const int* in_sizes, int n_in,
                              void* d_out, int out_size, void* d_ws, size_t ws_size,
                              hipStream_t stream) {
    const float* inputs = (const float*)d_in[0];
    const int*   seqlen = (const int*)d_in[1];
    const float* Wx     = (const float*)d_in[2];
    const float* Wh     = (const float*)d_in[3];
    const float* bias   = (const float*)d_in[4];
    float* out = (float*)d_out;

    char* ws = (char*)d_ws;
    size_t o = 0;
    bf16_t*   Wt    = (bf16_t*)(ws + o);   o += (size_t)N4H * KTOT * 2;   // 12.6MB
    unsigned* Xpk   = (unsigned*)(ws + o); o += (size_t)B_ * T_ * D_ * 4; // 33.6MB
    unsigned* hpk   = (unsigned*)(ws + o); o += (size_t)2 * B_ * H_ * 4;  // 256KB
    unsigned* flags = (unsigned*)(ws + o); o += 4096;

    wconv_kernel<<<dim3(48, 128), dim3(32, 8), 0, stream>>>(Wx, Wh, Wt);
    xconv_kernel<<<(B_ * T_ * D_ / 4) / 256, 256, 0, stream>>>(
        (const float4*)inputs, (uint4*)Xpk);
    hipMemsetAsync(hpk, 0, (size_t)B_ * H_ * 4, stream);  // ping p=0 zeros
    hipMemsetAsync(flags, 0, 4096, stream);               // wave flags

    lstm_kernel<<<NBLK, 512, 0, stream>>>(Wt, Xpk, hpk, bias, seqlen, out, flags);
}

// Round 13
// 2726.265 us; speedup vs baseline: 1.2984x; 1.2650x over previous
//
#include <hip/hip_runtime.h>
#include <hip/hip_bf16.h>

// LSTM B=32,T=512,D=512,H=1024, persistent kernel.
// R16 = R11 + NO-REUSE h slots -> consumer h reads become plain CACHED
// loads (L2-shared within each XCD), no fence needed.
//  Theory: R11's h reads are agent-scope (L2-bypass) -> every block pulls
//  the full 128KB h tile from L3 every step = 8MB/step, ~131K line-txns,
//  ALL L3-served. That transaction pressure (~2.6us/step) is the gap
//  between the ~2.5us protocol-chain model and the measured 6.4us.
//  Fix: 513 h slots, descending addresses, each written once and read
//  once per XCD-L2. Virgin addresses -> no stale L1/L2 copy can exist ->
//  plain cached loads are CORRECT: producer sc1 stores drain to L3
//  before the flag; consumer's L2 miss fills from L3 with fresh data.
//  First toucher per XCD fills L2, other blocks hit L2: L3 txns drop 8x.
//  - Descending slot order: forward streaming prefetch only crosses into
//    already-consumed (older) slots, never future ones.
//  - h-write path, flags, subset poll, stage, x-part: EXACTLY R11.
//  - Guard: ws_size < ~114MB -> XP=0 fallback = exact R11 (3275us).
//  - R14/R15 lessons kept: no xproj producers (compute is hidden), keep
//    R11's wave0-consolidated store (R15's scatter was slightly worse).

#define B_   32
#define T_   512
#define D_   512
#define H_   1024
#define KTOT 1536
#define N4H  4096
#define NBLK 64
#define NSLOT 513

typedef __bf16 bf16_t;
typedef __bf16 bf16x8 __attribute__((ext_vector_type(8)));
typedef float f32x4 __attribute__((ext_vector_type(4)));

#define MFMA16(a, b, c) __builtin_amdgcn_mfma_f32_16x16x32_bf16(a, b, c, 0, 0, 0)

// ---------------------------------------------------------------------------
__global__ void wconv_kernel(const float* __restrict__ Wx,
                             const float* __restrict__ Wh,
                             bf16_t* __restrict__ Wt) {
    __shared__ float tile[32][33];
    int k0 = blockIdx.x * 32;
    int n0 = blockIdx.y * 32;
    int tx = threadIdx.x;
    int ty = threadIdx.y;
    for (int i = ty; i < 32; i += 8) {
        int k = k0 + i;
        float v = (k < H_) ? Wh[(size_t)k * N4H + n0 + tx]
                           : Wx[(size_t)(k - H_) * N4H + n0 + tx];
        tile[i][tx] = v;
    }
    __syncthreads();
    for (int i = ty; i < 32; i += 8)
        Wt[(size_t)(n0 + i) * KTOT + k0 + tx] = (bf16_t)tile[tx][i];
}

// ---------------------------------------------------------------------------
// X -> packed uint32 per element: low16 = bf16(hi), high16 = bf16(residual).
__global__ void xconv_kernel(const float4* __restrict__ X,
                             uint4* __restrict__ Xpk) {
    int i = blockIdx.x * blockDim.x + threadIdx.x;
    float4 v = X[i];
    float arr[4] = {v.x, v.y, v.z, v.w};
    unsigned pk[4];
#pragma unroll
    for (int j = 0; j < 4; ++j) {
        bf16_t h = (bf16_t)arr[j];
        bf16_t l = (bf16_t)(arr[j] - (float)h);
        pk[j] = (unsigned)__builtin_bit_cast(unsigned short, h) |
                ((unsigned)__builtin_bit_cast(unsigned short, l) << 16);
    }
    Xpk[i] = make_uint4(pk[0], pk[1], pk[2], pk[3]);
}

// ---------------------------------------------------------------------------
__device__ __forceinline__ void unpack16(const unsigned short* s,
                                         bf16x8* hi, bf16x8* lo) {
#pragma unroll
    for (int j = 0; j < 8; ++j) {
        (*hi)[j] = __builtin_bit_cast(bf16_t, s[2 * j]);
        (*lo)[j] = __builtin_bit_cast(bf16_t, s[2 * j + 1]);
    }
}

// ---------------------------------------------------------------------------
// Block b owns h-cols [16b,16b+16). Wave w: h-k in [128w,128w+128) (4 kb,
// producers = blocks 8w..8w+7) + x-k in [1024+64w,1024+64w+64) (2 kb).
// XP=1: h slots never reused; reads are plain cached loads. XP=0: R11
// ping-pong with agent-scope loads.
template <int XP>
__global__ __launch_bounds__(512, 1) void lstm_kernel(
    const bf16_t* __restrict__ Wt,
    const unsigned* __restrict__ Xpk,
    unsigned* __restrict__ hpk,
    const float* __restrict__ bias,
    const int* __restrict__ seqlen,
    float* __restrict__ out,
    unsigned* __restrict__ flags) {
    __shared__ float zpart[8][4][32][16];  // 64 KB partial sums (stride 16:
                                           // epilogue reads exactly 2-way)
    __shared__ unsigned stage[512];        // 2 KB h-store stage

    const int tid  = threadIdx.x;
    const int w    = tid >> 6;
    const int lane = tid & 63;
    const int quad = lane >> 4;
    const int lcol = lane & 15;
    const int hc0  = blockIdx.x * 16;
    const int HW_  = 32768;                // uints per h slot (B_*H_)

    // Weight fragments: 4 gates x 6 k-iters (4 h + 2 x), loaded once.
    bf16x8 wreg[24];
#pragma unroll
    for (int g = 0; g < 4; ++g)
#pragma unroll
        for (int it = 0; it < 6; ++it) {
            int k = (it < 4) ? (w * 128 + it * 32)
                             : (1024 + w * 64 + (it - 4) * 32);
            wreg[g * 6 + it] = *(const bf16x8*)(
                Wt + (size_t)(g * H_ + hc0 + lcol) * KTOT + k + quad * 8);
        }

    // Epilogue mapping: 512 threads = one (batch,col) element each.
    const int eb = tid >> 4, ec = tid & 15;
    const int col = hc0 + ec;
    float creg = 0.f;
    const float b0 = bias[col];
    const float b1 = bias[H_ + col];
    const float b2 = bias[2 * H_ + col];
    const float b3 = bias[3 * H_ + col];
    const int slm1 = seqlen[eb] - 1;
    // LDS stage index (destination-ordered within this block's h region).
    const int stageIdx = (eb >> 4) * 256 + ((ec >> 3) * 16 + (eb & 15)) * 8 +
                         (ec & 7);
    // Wave0 store-phase constants (ull index within an h slot).
    const int kbB  = (hc0 >> 5) * 1024;
    const int qlo  = (hc0 >> 4) & 1;
    const int QU   = (kbB >> 1) + qlo * 128;
    // Flag slots: producer block b -> flags[(b>>3)*16 + (b&7)] (64B/group).
    const int myflag = ((blockIdx.x >> 3) << 4) | (blockIdx.x & 7);
    const unsigned* pollp = flags + w * 16 + (lane & 7);

#pragma unroll 1
    for (int t = 0; t < T_; ++t) {
        // XP=1: descending no-reuse slots (read 512-t, write 511-t).
        // XP=0: R11 ping-pong (read t&1, write (t+1)&1).
        const unsigned* hr = hpk + (size_t)(XP ? (512 - t) : (t & 1)) * HW_;
        unsigned*       hw = hpk + (size_t)(XP ? (511 - t) : ((t + 1) & 1)) * HW_;

        f32x4 acc[8];
#pragma unroll
        for (int i = 0; i < 8; ++i) acc[i] = (f32x4){0.f, 0.f, 0.f, 0.f};

        // ---- x part: independent of h(t-1), fills the wait window ----
#pragma unroll
        for (int itx = 0; itx < 2; ++itx) {
            int kx = w * 64 + itx * 32 + quad * 8;
            union { uint4 q[2]; unsigned short s[16]; } u0, u1;
            const unsigned* p0 = Xpk + ((size_t)lcol * T_ + t) * D_ + kx;
            const unsigned* p1 = Xpk + ((size_t)(lcol + 16) * T_ + t) * D_ + kx;
            u0.q[0] = *(const uint4*)p0;
            u0.q[1] = *(const uint4*)(p0 + 4);
            u1.q[0] = *(const uint4*)p1;
            u1.q[1] = *(const uint4*)(p1 + 4);
            bf16x8 a0h, a0l, a1h, a1l;
            unpack16(u0.s, &a0h, &a0l);
            unpack16(u1.s, &a1h, &a1l);
#pragma unroll
            for (int g = 0; g < 4; ++g) {
                bf16x8 wv = wreg[g * 6 + 4 + itx];
                acc[g * 2]     = MFMA16(a0h, wv, acc[g * 2]);
                acc[g * 2]     = MFMA16(a0l, wv, acc[g * 2]);
                acc[g * 2 + 1] = MFMA16(a1h, wv, acc[g * 2 + 1]);
                acc[g * 2 + 1] = MFMA16(a1l, wv, acc[g * 2 + 1]);
            }
        }

        // ---- wait for THIS wave's 8 producers only (tight spin) ----
        {
            const unsigned tgt = (unsigned)t;
            for (;;) {
                unsigned v = __hip_atomic_load(pollp, __ATOMIC_RELAXED,
                                               __HIP_MEMORY_SCOPE_AGENT);
                if (__all((int)(v >= tgt))) break;
            }
            asm volatile("" ::: "memory");
        }

        // ---- h part: 8 fragments. XP=1: plain cached loads (virgin
        //      addresses, L2-shared per XCD). XP=0: agent-scope atomics.
        union Raw { uint4 q[2]; unsigned long long u[4]; unsigned short s[16]; };
        Raw r[8];
        if (XP) {
#pragma unroll
            for (int it = 0; it < 4; ++it) {
                const uint4* q =
                    (const uint4*)(hr + (w * 4 + it) * 1024 + lane * 8);
                r[it * 2].q[0]     = q[0];
                r[it * 2].q[1]     = q[1];
                r[it * 2 + 1].q[0] = q[128];   // +512 uints = batches 16..31
                r[it * 2 + 1].q[1] = q[129];
            }
        } else {
#pragma unroll
            for (int it = 0; it < 4; ++it) {
                const unsigned long long* q = (const unsigned long long*)(
                    hr + (w * 4 + it) * 1024 + lane * 8);
#pragma unroll
                for (int j = 0; j < 4; ++j)
                    r[it * 2].u[j] = __hip_atomic_load(
                        q + j, __ATOMIC_RELAXED, __HIP_MEMORY_SCOPE_AGENT);
#pragma unroll
                for (int j = 0; j < 4; ++j)
                    r[it * 2 + 1].u[j] = __hip_atomic_load(
                        q + 256 + j, __ATOMIC_RELAXED, __HIP_MEMORY_SCOPE_AGENT);
            }
        }
#pragma unroll
        for (int it = 0; it < 4; ++it) {
            bf16x8 a0h, a0l, a1h, a1l;
            unpack16(r[it * 2].s, &a0h, &a0l);
            unpack16(r[it * 2 + 1].s, &a1h, &a1l);
#pragma unroll
            for (int g = 0; g < 4; ++g) {
                bf16x8 wv = wreg[g * 6 + it];
                acc[g * 2]     = MFMA16(a0h, wv, acc[g * 2]);
                acc[g * 2]     = MFMA16(a0l, wv, acc[g * 2]);
                acc[g * 2 + 1] = MFMA16(a1h, wv, acc[g * 2 + 1]);
                acc[g * 2 + 1] = MFMA16(a1l, wv, acc[g * 2 + 1]);
            }
        }

#pragma unroll
        for (int g = 0; g < 4; ++g)
#pragma unroll
            for (int r4 = 0; r4 < 4; ++r4) {
                zpart[w][g][quad * 4 + r4][lcol]      = acc[g * 2][r4];
                zpart[w][g][16 + quad * 4 + r4][lcol] = acc[g * 2 + 1][r4];
            }
        __syncthreads();  // A: zpart complete

        // Epilogue (all 512 threads).
        float zi = b0, zf = b1, zg = b2, zo = b3;
#pragma unroll
        for (int ss = 0; ss < 8; ++ss) {
            zi += zpart[ss][0][eb][ec];
            zf += zpart[ss][1][eb][ec];
            zg += zpart[ss][2][eb][ec];
            zo += zpart[ss][3][eb][ec];
        }
        float ig = 1.f / (1.f + __expf(-zi));
        float fg = 1.f / (1.f + __expf(-zf));
        float og = 1.f / (1.f + __expf(-zo));
        float gg = 1.f - 2.f / (__expf(2.f * zg) + 1.f);
        creg = fg * creg + ig * gg;
        float hn = og * (1.f - 2.f / (__expf(2.f * creg) + 1.f));
        bf16_t hh = (bf16_t)hn;
        bf16_t hl = (bf16_t)(hn - (float)hh);
        unsigned pk = (unsigned)__builtin_bit_cast(unsigned short, hh) |
                      ((unsigned)__builtin_bit_cast(unsigned short, hl) << 16);
        stage[stageIdx] = pk;
        if (slm1 == t) out[eb * H_ + col] = hn;

        __syncthreads();  // C: stage complete (zpart reads also done)

        // Wave 0 alone: 4 rounds x contiguous 512B of 8B agent atomic
        // stores, drain OWN vmcnt, post flag. Waves 1-7 race ahead.
        if (w == 0) {
            const unsigned long long* sp = (const unsigned long long*)stage;
            unsigned long long* hwu = (unsigned long long*)hw;
#pragma unroll
            for (int j = 0; j < 4; ++j) {
                unsigned long long val = sp[j * 64 + lane];
                __hip_atomic_store(
                    hwu + QU + (j >> 1) * 256 + (j & 1) * 64 + lane, val,
                    __ATOMIC_RELAXED, __HIP_MEMORY_SCOPE_AGENT);
            }
            asm volatile("s_waitcnt vmcnt(0)" ::: "memory");
            if (lane == 0)
                __hip_atomic_store(flags + myflag, (unsigned)(t + 1),
                                   __ATOMIC_RELAXED, __HIP_MEMORY_SCOPE_AGENT);
        }
    }
}

// ---------------------------------------------------------------------------
extern "C" void kernel_launch(void* const* d_in, const int* in_sizes, int n_in,
                              void* d_out, int out_size, void* d_ws, size_t ws_size,
                              hipStream_t stream) {
    const float* inputs = (const float*)d_in[0];
    const int*   seqlen = (const int*)d_in[1];
    const float* Wx     = (const float*)d_in[2];
    const float* Wh     = (const float*)d_in[3];
    const float* bias   = (const float*)d_in[4];
    float* out = (float*)d_out;

    char* ws = (char*)d_ws;
    size_t o = 0;
    bf16_t*   Wt    = (bf16_t*)(ws + o);   o += (size_t)N4H * KTOT * 2;   // 12.6MB
    unsigned* Xpk   = (unsigned*)(ws + o); o += (size_t)B_ * T_ * D_ * 4; // 33.6MB
    unsigned* flags = (unsigned*)(ws + o); o += 4096;
    unsigned* hpk   = (unsigned*)(ws + o);
    const size_t slotB = (size_t)B_ * H_ * 4;           // 128KB per slot
    const size_t NEED  = o + (size_t)NSLOT * slotB;     // ~113.5MB total
    const bool use_xp  = ws_size >= NEED;

    wconv_kernel<<<dim3(48, 128), dim3(32, 8), 0, stream>>>(Wx, Wh, Wt);
    xconv_kernel<<<(B_ * T_ * D_ / 4) / 256, 256, 0, stream>>>(
        (const float4*)inputs, (uint4*)Xpk);
    hipMemsetAsync(flags, 0, 4096, stream);
    if (use_xp) {
        // Zero slot = slot index 512 (read at t=0).
        hipMemsetAsync(hpk + (size_t)512 * B_ * H_, 0, slotB, stream);
        lstm_kernel<1><<<NBLK, 512, 0, stream>>>(Wt, Xpk, hpk, bias, seqlen,
                                                 out, flags);
    } else {
        hipMemsetAsync(hpk, 0, slotB, stream);  // ping slot 0
        lstm_kernel<0><<<NBLK, 512, 0, stream>>>(Wt, Xpk, hpk, bias, seqlen,
                                                 out, flags);
    }
}